// Round 1
// baseline (1182.758 us; speedup 1.0000x reference)
//
#include <hip/hip_runtime.h>

#define N_NODES 10000
#define N_EDGES 320000
#define F 256          // F_IN == F_OUT
#define K2 512         // 2*F_IN
#define BN 16          // nodes per block in GEMM kernel

// ---------------- edge aggregation: agg[d] += ew[e] * feat[src[e]], cnt[d] += 1
__global__ __launch_bounds__(256) void edge_agg_kernel(
    const float* __restrict__ feat,
    const float* __restrict__ ew,
    const int* __restrict__ src,
    const int* __restrict__ dst,
    float* __restrict__ agg,
    float* __restrict__ cnt) {
  int wave = (blockIdx.x * 256 + threadIdx.x) >> 6;  // one wave per edge
  int lane = threadIdx.x & 63;
  if (wave >= N_EDGES) return;
  int s = src[wave];
  int d = dst[wave];
  float w = ew[wave];
  const float4* f4 = (const float4*)(feat + (size_t)s * F);
  float4 v = f4[lane];                                // lane covers 4 floats
  float* a = agg + (size_t)d * F + lane * 4;
  unsafeAtomicAdd(a + 0, v.x * w);
  unsafeAtomicAdd(a + 1, v.y * w);
  unsafeAtomicAdd(a + 2, v.z * w);
  unsafeAtomicAdd(a + 3, v.w * w);
  if (lane == 0) unsafeAtomicAdd(cnt + d, 1.0f);
}

// ---------------- fused: hm_mean = h0*agg/max(cnt,1); out = relu([feat|hm] @ W.T + b)
__global__ __launch_bounds__(256) void gemm_relu_kernel(
    const float* __restrict__ feat,
    const int* __restrict__ src,
    const float* __restrict__ agg,
    const float* __restrict__ cnt,
    const float* __restrict__ Wm,
    const float* __restrict__ bias,
    float* __restrict__ out) {
  __shared__ float xs[BN * K2];    // 16 nodes x 512 = 32 KB
  __shared__ float h0s[F];

  int tid = threadIdx.x;
  int n0 = blockIdx.x * BN;
  int s0 = src[0];

  // stage h0 = feat[src[0]]
  if (tid < F / 4) {
    ((float4*)h0s)[tid] = ((const float4*)(feat + (size_t)s0 * F))[tid];
  }
  __syncthreads();

  // stage x = [feat[n] | h0*agg[n]/max(cnt,1)] : 2048 float4s, 8 per thread
  for (int j = 0; j < 8; ++j) {
    int idx = tid + 256 * j;       // float4 index into xs
    int n = idx >> 7;              // 128 float4 per row
    int c4 = idx & 127;
    int node = n0 + n;
    float4 v = make_float4(0.f, 0.f, 0.f, 0.f);
    if (node < N_NODES) {
      if (c4 < 64) {
        v = ((const float4*)(feat + (size_t)node * F))[c4];
      } else {
        float ic = 1.0f / fmaxf(cnt[node], 1.0f);
        float4 a = ((const float4*)(agg + (size_t)node * F))[c4 - 64];
        float4 h = ((const float4*)h0s)[c4 - 64];
        v = make_float4(a.x * h.x * ic, a.y * h.y * ic,
                        a.z * h.z * ic, a.w * h.w * ic);
      }
    }
    ((float4*)xs)[idx] = v;
  }
  __syncthreads();

  // thread t computes output column o = t for all BN nodes
  float acc[BN];
  float bv = bias[tid];
#pragma unroll
  for (int n = 0; n < BN; ++n) acc[n] = bv;

  const float4* Wrow = (const float4*)(Wm + (size_t)tid * K2);
  for (int k4 = 0; k4 < K2 / 4; ++k4) {
    float4 w = Wrow[k4];
#pragma unroll
    for (int n = 0; n < BN; ++n) {
      float4 x = ((const float4*)xs)[n * (K2 / 4) + k4];  // wave-broadcast
      acc[n] += w.x * x.x + w.y * x.y + w.z * x.z + w.w * x.w;
    }
  }

#pragma unroll
  for (int n = 0; n < BN; ++n) {
    int node = n0 + n;
    if (node < N_NODES)
      out[(size_t)node * F + tid] = fmaxf(acc[n], 0.0f);
  }
}

extern "C" void kernel_launch(void* const* d_in, const int* in_sizes, int n_in,
                              void* d_out, int out_size, void* d_ws, size_t ws_size,
                              hipStream_t stream) {
  const float* feat = (const float*)d_in[0];
  const float* ew   = (const float*)d_in[1];
  const int*   src  = (const int*)d_in[2];
  const int*   dst  = (const int*)d_in[3];
  const float* Wm   = (const float*)d_in[4];
  const float* bias = (const float*)d_in[5];
  float* out = (float*)d_out;

  float* agg = (float*)d_ws;                     // N_NODES * F floats
  float* cnt = agg + (size_t)N_NODES * F;        // N_NODES floats

  size_t zero_bytes = ((size_t)N_NODES * F + N_NODES) * sizeof(float);
  hipMemsetAsync(d_ws, 0, zero_bytes, stream);

  int edge_blocks = (N_EDGES * 64 + 255) / 256;  // one wave per edge
  edge_agg_kernel<<<edge_blocks, 256, 0, stream>>>(feat, ew, src, dst, agg, cnt);

  int gemm_blocks = (N_NODES + BN - 1) / BN;
  gemm_relu_kernel<<<gemm_blocks, 256, 0, stream>>>(feat, src, agg, cnt, Wm, bias, out);
}

// Round 2
// 200.218 us; speedup vs baseline: 5.9074x; 5.9074x over previous
//
#include <hip/hip_runtime.h>

#define N_NODES 10000
#define N_EDGES 320000
#define F 256          // F_IN == F_OUT
#define K2 512         // 2*F_IN
#define BN 16          // nodes per block in GEMM kernel
#define SCAN_T 256
#define SCAN_CH 40     // 256*40 = 10240 >= N_NODES

// ---------- CSR build step 1: histogram of dst
__global__ __launch_bounds__(256) void hist_kernel(const int* __restrict__ dst,
                                                   int* __restrict__ deg) {
  int e = blockIdx.x * 256 + threadIdx.x;
  if (e < N_EDGES) atomicAdd(&deg[dst[e]], 1);
}

// ---------- CSR build step 2: exclusive scan (single block)
__global__ __launch_bounds__(SCAN_T) void scan_kernel(const int* __restrict__ deg,
                                                      int* __restrict__ off,
                                                      int* __restrict__ cursor) {
  __shared__ int part[SCAN_T];
  int t = threadIdx.x;
  int base = t * SCAN_CH;
  int local[SCAN_CH];
  int s = 0;
  for (int j = 0; j < SCAN_CH; ++j) {
    int i = base + j;
    int d = (i < N_NODES) ? deg[i] : 0;
    local[j] = s;
    s += d;
  }
  part[t] = s;
  __syncthreads();
  for (int ofs = 1; ofs < SCAN_T; ofs <<= 1) {
    int v = (t >= ofs) ? part[t - ofs] : 0;
    __syncthreads();
    part[t] += v;
    __syncthreads();
  }
  int excl = part[t] - s;
  for (int j = 0; j < SCAN_CH; ++j) {
    int i = base + j;
    if (i < N_NODES) {
      int o = excl + local[j];
      off[i] = o;
      cursor[i] = o;
    }
  }
  if (t == SCAN_T - 1) off[N_NODES] = part[SCAN_T - 1];
}

// ---------- CSR build step 3: scatter (src, ew) into dst-sorted order
__global__ __launch_bounds__(256) void scatter_kernel(const int* __restrict__ src,
                                                      const int* __restrict__ dst,
                                                      const float* __restrict__ ew,
                                                      int* __restrict__ cursor,
                                                      int* __restrict__ esrc,
                                                      float* __restrict__ eww) {
  int e = blockIdx.x * 256 + threadIdx.x;
  if (e >= N_EDGES) return;
  int d = dst[e];
  int p = atomicAdd(&cursor[d], 1);
  esrc[p] = src[e];
  eww[p] = ew[e];
}

// ---------- aggregation: one wave per node, register accumulation, no atomics
// writes agg[n] = mean over incoming edges of ew*feat[src]  (h0 applied in GEMM)
__global__ __launch_bounds__(256) void node_agg_kernel(
    const float* __restrict__ feat,
    const int* __restrict__ off,
    const int* __restrict__ esrc,
    const float* __restrict__ eww,
    float* __restrict__ agg) {
  int node = (blockIdx.x * 256 + threadIdx.x) >> 6;
  int lane = threadIdx.x & 63;
  if (node >= N_NODES) return;
  int beg = off[node], end = off[node + 1];
  float4 acc = make_float4(0.f, 0.f, 0.f, 0.f);
  const float4* f4 = (const float4*)feat;
  int i = beg;
  // 2-deep manual pipeline for latency hiding
  for (; i + 2 <= end; i += 2) {
    int s0 = esrc[i], s1 = esrc[i + 1];
    float w0 = eww[i], w1 = eww[i + 1];
    float4 v0 = f4[(size_t)s0 * 64 + lane];
    float4 v1 = f4[(size_t)s1 * 64 + lane];
    acc.x += v0.x * w0 + v1.x * w1;
    acc.y += v0.y * w0 + v1.y * w1;
    acc.z += v0.z * w0 + v1.z * w1;
    acc.w += v0.w * w0 + v1.w * w1;
  }
  for (; i < end; ++i) {
    int s = esrc[i];
    float w = eww[i];
    float4 v = f4[(size_t)s * 64 + lane];
    acc.x += v.x * w; acc.y += v.y * w; acc.z += v.z * w; acc.w += v.w * w;
  }
  float ic = 1.0f / (float)max(end - beg, 1);
  acc.x *= ic; acc.y *= ic; acc.z *= ic; acc.w *= ic;
  ((float4*)agg)[(size_t)node * 64 + lane] = acc;
}

// ---------- fused: hm = h0*agg (agg already mean); out = relu([feat|hm] @ W.T + b)
__global__ __launch_bounds__(256) void gemm_relu_kernel(
    const float* __restrict__ feat,
    const int* __restrict__ src,
    const float* __restrict__ agg,
    const float* __restrict__ Wm,
    const float* __restrict__ bias,
    float* __restrict__ out) {
  __shared__ float xs[BN * K2];    // 16 nodes x 512 = 32 KB
  __shared__ float h0s[F];

  int tid = threadIdx.x;
  int n0 = blockIdx.x * BN;
  int s0 = src[0];

  if (tid < F / 4) {
    ((float4*)h0s)[tid] = ((const float4*)(feat + (size_t)s0 * F))[tid];
  }
  __syncthreads();

  for (int j = 0; j < 8; ++j) {
    int idx = tid + 256 * j;       // float4 index into xs
    int n = idx >> 7;              // 128 float4 per row
    int c4 = idx & 127;
    int node = n0 + n;
    float4 v = make_float4(0.f, 0.f, 0.f, 0.f);
    if (node < N_NODES) {
      if (c4 < 64) {
        v = ((const float4*)(feat + (size_t)node * F))[c4];
      } else {
        float4 a = ((const float4*)(agg + (size_t)node * F))[c4 - 64];
        float4 h = ((const float4*)h0s)[c4 - 64];
        v = make_float4(a.x * h.x, a.y * h.y, a.z * h.z, a.w * h.w);
      }
    }
    ((float4*)xs)[idx] = v;
  }
  __syncthreads();

  float acc[BN];
  float bv = bias[tid];
#pragma unroll
  for (int n = 0; n < BN; ++n) acc[n] = bv;

  const float4* Wrow = (const float4*)(Wm + (size_t)tid * K2);
  for (int k4 = 0; k4 < K2 / 4; ++k4) {
    float4 w = Wrow[k4];
#pragma unroll
    for (int n = 0; n < BN; ++n) {
      float4 x = ((const float4*)xs)[n * (K2 / 4) + k4];
      acc[n] += w.x * x.x + w.y * x.y + w.z * x.z + w.w * x.w;
    }
  }

#pragma unroll
  for (int n = 0; n < BN; ++n) {
    int node = n0 + n;
    if (node < N_NODES)
      out[(size_t)node * F + tid] = fmaxf(acc[n], 0.0f);
  }
}

extern "C" void kernel_launch(void* const* d_in, const int* in_sizes, int n_in,
                              void* d_out, int out_size, void* d_ws, size_t ws_size,
                              hipStream_t stream) {
  const float* feat = (const float*)d_in[0];
  const float* ew   = (const float*)d_in[1];
  const int*   src  = (const int*)d_in[2];
  const int*   dst  = (const int*)d_in[3];
  const float* Wm   = (const float*)d_in[4];
  const float* bias = (const float*)d_in[5];
  float* out = (float*)d_out;

  // workspace layout
  float* agg   = (float*)d_ws;                           // N*F floats (10.24 MB)
  int*   off   = (int*)(agg + (size_t)N_NODES * F);      // N+1
  int*   cursor= off + N_NODES + 1;                      // N
  int*   deg   = cursor + N_NODES;                       // N
  int*   esrc  = deg + N_NODES;                          // E
  float* eww   = (float*)(esrc + N_EDGES);               // E

  hipMemsetAsync(deg, 0, N_NODES * sizeof(int), stream);

  hist_kernel<<<(N_EDGES + 255) / 256, 256, 0, stream>>>(dst, deg);
  scan_kernel<<<1, SCAN_T, 0, stream>>>(deg, off, cursor);
  scatter_kernel<<<(N_EDGES + 255) / 256, 256, 0, stream>>>(src, dst, ew, cursor, esrc, eww);

  int agg_blocks = (N_NODES * 64 + 255) / 256;  // one wave per node
  node_agg_kernel<<<agg_blocks, 256, 0, stream>>>(feat, off, esrc, eww, agg);

  int gemm_blocks = (N_NODES + BN - 1) / BN;
  gemm_relu_kernel<<<gemm_blocks, 256, 0, stream>>>(feat, src, agg, Wm, bias, out);
}

// Round 3
// 141.389 us; speedup vs baseline: 8.3653x; 1.4161x over previous
//
#include <hip/hip_runtime.h>

#define N_NODES 10000
#define N_EDGES 320000
#define F 256          // F_IN == F_OUT
#define K2 512         // 2*F_IN
#define SCAN_T 256
#define SCAN_CH 40     // 256*40 = 10240 >= N_NODES

typedef __attribute__((ext_vector_type(8))) __bf16 bf16x8;
typedef __attribute__((ext_vector_type(4))) __bf16 bf16x4;
typedef __attribute__((ext_vector_type(4))) float f32x4;
typedef unsigned long long u64;
typedef unsigned int u32;
typedef unsigned short u16;

__device__ inline float bf2f(u16 u) { u32 x = ((u32)u) << 16; return __uint_as_float(x); }

// ---------- prep: feat f32 -> bf16
__global__ __launch_bounds__(256) void prep_feat_kernel(const float* __restrict__ feat,
                                                        __bf16* __restrict__ featb) {
  int idx = blockIdx.x * 256 + threadIdx.x;          // float4 index
  if (idx >= N_NODES * F / 4) return;
  float4 v = ((const float4*)feat)[idx];
  bf16x4 b;
  b[0] = (__bf16)v.x; b[1] = (__bf16)v.y; b[2] = (__bf16)v.z; b[3] = (__bf16)v.w;
  *(bf16x4*)(featb + (size_t)idx * 4) = b;
}

// ---------- prep: Wb[o][k] = bf16( W[o][k] * (k<F ? 1 : h0[k-F]) ),  h0 = feat[src[0]]
__global__ __launch_bounds__(256) void prep_w_kernel(const float* __restrict__ Wm,
                                                     const float* __restrict__ feat,
                                                     const int* __restrict__ src,
                                                     __bf16* __restrict__ Wb) {
  int idx = blockIdx.x * 256 + threadIdx.x;          // float4 index, total F*K2/4 = 32768
  if (idx >= F * K2 / 4) return;
  int k4 = idx & (K2 / 4 - 1);                       // 0..127
  float4 w = ((const float4*)Wm)[idx];
  if (k4 >= F / 4) {
    int s0 = src[0];
    float4 h = ((const float4*)(feat + (size_t)s0 * F))[k4 - F / 4];
    w.x *= h.x; w.y *= h.y; w.z *= h.z; w.w *= h.w;
  }
  bf16x4 b;
  b[0] = (__bf16)w.x; b[1] = (__bf16)w.y; b[2] = (__bf16)w.z; b[3] = (__bf16)w.w;
  *(bf16x4*)(Wb + (size_t)idx * 4) = b;
}

// ---------- CSR build step 1: histogram of dst
__global__ __launch_bounds__(256) void hist_kernel(const int* __restrict__ dst,
                                                   int* __restrict__ deg) {
  int e = blockIdx.x * 256 + threadIdx.x;
  if (e < N_EDGES) atomicAdd(&deg[dst[e]], 1);
}

// ---------- CSR build step 2: exclusive scan (single block)
__global__ __launch_bounds__(SCAN_T) void scan_kernel(const int* __restrict__ deg,
                                                      int* __restrict__ off,
                                                      int* __restrict__ cursor) {
  __shared__ int part[SCAN_T];
  int t = threadIdx.x;
  int base = t * SCAN_CH;
  int local[SCAN_CH];
  int s = 0;
  for (int j = 0; j < SCAN_CH; ++j) {
    int i = base + j;
    int d = (i < N_NODES) ? deg[i] : 0;
    local[j] = s;
    s += d;
  }
  part[t] = s;
  __syncthreads();
  for (int ofs = 1; ofs < SCAN_T; ofs <<= 1) {
    int v = (t >= ofs) ? part[t - ofs] : 0;
    __syncthreads();
    part[t] += v;
    __syncthreads();
  }
  int excl = part[t] - s;
  for (int j = 0; j < SCAN_CH; ++j) {
    int i = base + j;
    if (i < N_NODES) {
      int o = excl + local[j];
      off[i] = o;
      cursor[i] = o;
    }
  }
  if (t == SCAN_T - 1) off[N_NODES] = part[SCAN_T - 1];
}

// ---------- CSR build step 3: scatter packed (ew,src) into dst-sorted order
__global__ __launch_bounds__(256) void scatter_kernel(const int* __restrict__ src,
                                                      const int* __restrict__ dst,
                                                      const float* __restrict__ ew,
                                                      int* __restrict__ cursor,
                                                      u64* __restrict__ epack) {
  int e = blockIdx.x * 256 + threadIdx.x;
  if (e >= N_EDGES) return;
  int d = dst[e];
  int p = atomicAdd(&cursor[d], 1);
  u64 pk = ((u64)__float_as_uint(ew[e]) << 32) | (u32)src[e];
  epack[p] = pk;
}

// ---------- aggregation: one wave per node, bf16 gather, f32 accum, bf16 out
// aggb[n] = mean over incoming edges of ew * featb[src]   (h0 folded into Wb)
__global__ __launch_bounds__(256) void node_agg_kernel(
    const __bf16* __restrict__ featb,
    const int* __restrict__ off,
    const u64* __restrict__ epack,
    __bf16* __restrict__ aggb) {
  int node = (blockIdx.x * 256 + threadIdx.x) >> 6;
  int lane = threadIdx.x & 63;
  if (node >= N_NODES) return;
  int beg = off[node], end = off[node + 1];
  float ax = 0.f, ay = 0.f, az = 0.f, aw = 0.f;
  const ushort4* f4 = (const ushort4*)featb;        // 4 bf16 per lane-slot
  int i = beg;
  for (; i + 2 <= end; i += 2) {
    u64 p0 = epack[i], p1 = epack[i + 1];
    int s0 = (int)(u32)p0, s1 = (int)(u32)p1;
    float w0 = __uint_as_float((u32)(p0 >> 32));
    float w1 = __uint_as_float((u32)(p1 >> 32));
    ushort4 v0 = f4[(size_t)s0 * 64 + lane];
    ushort4 v1 = f4[(size_t)s1 * 64 + lane];
    ax += bf2f(v0.x) * w0 + bf2f(v1.x) * w1;
    ay += bf2f(v0.y) * w0 + bf2f(v1.y) * w1;
    az += bf2f(v0.z) * w0 + bf2f(v1.z) * w1;
    aw += bf2f(v0.w) * w0 + bf2f(v1.w) * w1;
  }
  for (; i < end; ++i) {
    u64 p0 = epack[i];
    int s0 = (int)(u32)p0;
    float w0 = __uint_as_float((u32)(p0 >> 32));
    ushort4 v0 = f4[(size_t)s0 * 64 + lane];
    ax += bf2f(v0.x) * w0; ay += bf2f(v0.y) * w0;
    az += bf2f(v0.z) * w0; aw += bf2f(v0.w) * w0;
  }
  float ic = 1.0f / (float)max(end - beg, 1);
  bf16x4 o;
  o[0] = (__bf16)(ax * ic); o[1] = (__bf16)(ay * ic);
  o[2] = (__bf16)(az * ic); o[3] = (__bf16)(aw * ic);
  *(bf16x4*)(aggb + (size_t)node * F + lane * 4) = o;
}

// ---------- MFMA GEMM: out = relu([featb | aggb] @ Wb.T + b), no LDS
// block = 16 rows x 256 cols, 4 waves; wave = 16 rows x 64 cols (4 col-tiles)
__global__ __launch_bounds__(256) void mfma_gemm_kernel(
    const __bf16* __restrict__ featb,   // [N][F]
    const __bf16* __restrict__ aggb,    // [N][F]
    const __bf16* __restrict__ Wb,      // [F_OUT][K2]
    const float* __restrict__ bias,
    float* __restrict__ out) {          // [N][F_OUT]
  int tid = threadIdx.x;
  int wave = tid >> 6;
  int lane = tid & 63;
  int m0 = blockIdx.x * 16;             // 625 * 16 == 10000 exactly
  int r15 = lane & 15;                  // A-row within M-tile / W out-channel within col-tile
  int kq = lane >> 4;                   // k-quarter
  int node = m0 + r15;
  int col0 = wave * 64;

  const __bf16* arow_f = featb + (size_t)node * F;
  const __bf16* arow_a = aggb + (size_t)node * F;

  f32x4 acc[4];
#pragma unroll
  for (int c = 0; c < 4; ++c) acc[c] = (f32x4){0.f, 0.f, 0.f, 0.f};

#pragma unroll
  for (int t = 0; t < 16; ++t) {
    int kk = t * 32 + kq * 8;           // global k for this lane's 8 elements
    bf16x8 a;
    if (t < 8) a = *(const bf16x8*)(arow_f + kk);
    else       a = *(const bf16x8*)(arow_a + (kk - F));
#pragma unroll
    for (int c = 0; c < 4; ++c) {
      const __bf16* brow = Wb + (size_t)(col0 + c * 16 + r15) * K2 + kk;
      bf16x8 b = *(const bf16x8*)brow;
      acc[c] = __builtin_amdgcn_mfma_f32_16x16x32_bf16(a, b, acc[c], 0, 0, 0);
    }
  }

  // C/D layout: col = lane&15, row = (lane>>4)*4 + reg   [m89-verified]
  int rbase = kq * 4;
#pragma unroll
  for (int c = 0; c < 4; ++c) {
    int col = col0 + c * 16 + r15;
    float bv = bias[col];
#pragma unroll
    for (int r = 0; r < 4; ++r) {
      int orow = m0 + rbase + r;
      out[(size_t)orow * F + col] = fmaxf(acc[c][r] + bv, 0.0f);
    }
  }
}

extern "C" void kernel_launch(void* const* d_in, const int* in_sizes, int n_in,
                              void* d_out, int out_size, void* d_ws, size_t ws_size,
                              hipStream_t stream) {
  const float* feat = (const float*)d_in[0];
  const float* ew   = (const float*)d_in[1];
  const int*   src  = (const int*)d_in[2];
  const int*   dst  = (const int*)d_in[3];
  const float* Wm   = (const float*)d_in[4];
  const float* bias = (const float*)d_in[5];
  float* out = (float*)d_out;

  // workspace layout (8B-aligned first)
  u64*    epack = (u64*)d_ws;                                  // E
  __bf16* featb = (__bf16*)(epack + N_EDGES);                  // N*F
  __bf16* aggb  = featb + (size_t)N_NODES * F;                 // N*F
  __bf16* Wb    = aggb + (size_t)N_NODES * F;                  // F*K2
  int*    off   = (int*)(Wb + (size_t)F * K2);                 // N+1
  int*    cursor= off + N_NODES + 1;                           // N
  int*    deg   = cursor + N_NODES;                            // N

  hipMemsetAsync(deg, 0, N_NODES * sizeof(int), stream);

  prep_feat_kernel<<<(N_NODES * F / 4 + 255) / 256, 256, 0, stream>>>(feat, featb);
  prep_w_kernel<<<(F * K2 / 4 + 255) / 256, 256, 0, stream>>>(Wm, feat, src, Wb);

  hist_kernel<<<(N_EDGES + 255) / 256, 256, 0, stream>>>(dst, deg);
  scan_kernel<<<1, SCAN_T, 0, stream>>>(deg, off, cursor);
  scatter_kernel<<<(N_EDGES + 255) / 256, 256, 0, stream>>>(src, dst, ew, cursor, epack);

  node_agg_kernel<<<(N_NODES * 64 + 255) / 256, 256, 0, stream>>>(featb, off, epack, aggb);

  mfma_gemm_kernel<<<N_NODES / 16, 256, 0, stream>>>(featb, aggb, Wb, bias, out);
}

// Round 4
// 117.611 us; speedup vs baseline: 10.0565x; 1.2022x over previous
//
#include <hip/hip_runtime.h>

#define N_NODES 10000
#define N_EDGES 320000
#define F 256          // F_IN == F_OUT
#define K2 512         // 2*F_IN
#define SCAN_T 1024
#define SCAN_CH 10     // 1024*10 = 10240 >= N_NODES

#define FEAT_BLOCKS (N_NODES * F / 4 / 256)   // 2500
#define W_BLOCKS (F * K2 / 4 / 256)           // 128

typedef __attribute__((ext_vector_type(8))) __bf16 bf16x8;
typedef __attribute__((ext_vector_type(4))) __bf16 bf16x4;
typedef __attribute__((ext_vector_type(4))) float f32x4;
typedef unsigned long long u64;
typedef unsigned int u32;
typedef unsigned short u16;

__device__ inline float bf2f(u16 u) { u32 x = ((u32)u) << 16; return __uint_as_float(x); }

// ---------- fused prep: feat->bf16, W->bf16 (h0 folded), deg=0
__global__ __launch_bounds__(256) void prep_all_kernel(
    const float* __restrict__ feat,
    const float* __restrict__ Wm,
    const int* __restrict__ src,
    __bf16* __restrict__ featb,
    __bf16* __restrict__ Wb,
    int* __restrict__ deg) {
  int b = blockIdx.x;
  int tid = threadIdx.x;
  if (b < FEAT_BLOCKS) {
    int idx = b * 256 + tid;                         // float4 index
    float4 v = ((const float4*)feat)[idx];
    bf16x4 o;
    o[0] = (__bf16)v.x; o[1] = (__bf16)v.y; o[2] = (__bf16)v.z; o[3] = (__bf16)v.w;
    *(bf16x4*)(featb + (size_t)idx * 4) = o;
    if (idx < N_NODES) deg[idx] = 0;
  } else {
    int idx = (b - FEAT_BLOCKS) * 256 + tid;         // float4 index into W
    int k4 = idx & (K2 / 4 - 1);                     // 0..127
    float4 w = ((const float4*)Wm)[idx];
    if (k4 >= F / 4) {
      int s0 = src[0];
      float4 h = ((const float4*)(feat + (size_t)s0 * F))[k4 - F / 4];
      w.x *= h.x; w.y *= h.y; w.z *= h.z; w.w *= h.w;
    }
    bf16x4 o;
    o[0] = (__bf16)w.x; o[1] = (__bf16)w.y; o[2] = (__bf16)w.z; o[3] = (__bf16)w.w;
    *(bf16x4*)(Wb + (size_t)idx * 4) = o;
  }
}

// ---------- CSR build step 1: histogram of dst
__global__ __launch_bounds__(256) void hist_kernel(const int* __restrict__ dst,
                                                   int* __restrict__ deg) {
  int e = blockIdx.x * 256 + threadIdx.x;
  if (e < N_EDGES) atomicAdd(&deg[dst[e]], 1);
}

// ---------- CSR build step 2: exclusive scan (single block, 1024 thr)
__global__ __launch_bounds__(SCAN_T) void scan_kernel(const int* __restrict__ deg,
                                                      int* __restrict__ off,
                                                      int* __restrict__ cursor) {
  __shared__ int part[SCAN_T];
  int t = threadIdx.x;
  int base = t * SCAN_CH;
  int local[SCAN_CH];
  int s = 0;
  for (int j = 0; j < SCAN_CH; ++j) {
    int i = base + j;
    int d = (i < N_NODES) ? deg[i] : 0;
    local[j] = s;
    s += d;
  }
  part[t] = s;
  __syncthreads();
  for (int ofs = 1; ofs < SCAN_T; ofs <<= 1) {
    int v = (t >= ofs) ? part[t - ofs] : 0;
    __syncthreads();
    part[t] += v;
    __syncthreads();
  }
  int excl = part[t] - s;
  for (int j = 0; j < SCAN_CH; ++j) {
    int i = base + j;
    if (i < N_NODES) {
      int o = excl + local[j];
      off[i] = o;
      cursor[i] = o;
    }
  }
  if (t == SCAN_T - 1) off[N_NODES] = part[SCAN_T - 1];
}

// ---------- CSR build step 3: scatter packed (ew,src) into dst-sorted order
__global__ __launch_bounds__(256) void scatter_kernel(const int* __restrict__ src,
                                                      const int* __restrict__ dst,
                                                      const float* __restrict__ ew,
                                                      int* __restrict__ cursor,
                                                      u64* __restrict__ epack) {
  int e = blockIdx.x * 256 + threadIdx.x;
  if (e >= N_EDGES) return;
  int d = dst[e];
  int p = atomicAdd(&cursor[d], 1);
  u64 pk = ((u64)__float_as_uint(ew[e]) << 32) | (u32)src[e];
  epack[p] = pk;
}

// ---------- aggregation: one wave per node, 4-deep pipelined bf16 gather
__global__ __launch_bounds__(256) void node_agg_kernel(
    const __bf16* __restrict__ featb,
    const int* __restrict__ off,
    const u64* __restrict__ epack,
    __bf16* __restrict__ aggb) {
  int node = (blockIdx.x * 256 + threadIdx.x) >> 6;
  int lane = threadIdx.x & 63;
  if (node >= N_NODES) return;
  int beg = off[node], end = off[node + 1];
  float ax = 0.f, ay = 0.f, az = 0.f, aw = 0.f;
  const ushort4* f4 = (const ushort4*)featb;
  int i = beg;
  for (; i + 4 <= end; i += 4) {
    u64 p0 = epack[i], p1 = epack[i + 1], p2 = epack[i + 2], p3 = epack[i + 3];
    ushort4 v0 = f4[(size_t)(u32)p0 * 64 + lane];
    ushort4 v1 = f4[(size_t)(u32)p1 * 64 + lane];
    ushort4 v2 = f4[(size_t)(u32)p2 * 64 + lane];
    ushort4 v3 = f4[(size_t)(u32)p3 * 64 + lane];
    float w0 = __uint_as_float((u32)(p0 >> 32));
    float w1 = __uint_as_float((u32)(p1 >> 32));
    float w2 = __uint_as_float((u32)(p2 >> 32));
    float w3 = __uint_as_float((u32)(p3 >> 32));
    ax += bf2f(v0.x) * w0 + bf2f(v1.x) * w1 + bf2f(v2.x) * w2 + bf2f(v3.x) * w3;
    ay += bf2f(v0.y) * w0 + bf2f(v1.y) * w1 + bf2f(v2.y) * w2 + bf2f(v3.y) * w3;
    az += bf2f(v0.z) * w0 + bf2f(v1.z) * w1 + bf2f(v2.z) * w2 + bf2f(v3.z) * w3;
    aw += bf2f(v0.w) * w0 + bf2f(v1.w) * w1 + bf2f(v2.w) * w2 + bf2f(v3.w) * w3;
  }
  for (; i < end; ++i) {
    u64 p0 = epack[i];
    ushort4 v0 = f4[(size_t)(u32)p0 * 64 + lane];
    float w0 = __uint_as_float((u32)(p0 >> 32));
    ax += bf2f(v0.x) * w0; ay += bf2f(v0.y) * w0;
    az += bf2f(v0.z) * w0; aw += bf2f(v0.w) * w0;
  }
  float ic = 1.0f / (float)max(end - beg, 1);
  bf16x4 o;
  o[0] = (__bf16)(ax * ic); o[1] = (__bf16)(ay * ic);
  o[2] = (__bf16)(az * ic); o[3] = (__bf16)(aw * ic);
  *(bf16x4*)(aggb + (size_t)node * F + lane * 4) = o;
}

// ---------- MFMA GEMM: out = relu([featb | aggb] @ Wb.T + b), no LDS
__global__ __launch_bounds__(256) void mfma_gemm_kernel(
    const __bf16* __restrict__ featb,   // [N][F]
    const __bf16* __restrict__ aggb,    // [N][F]
    const __bf16* __restrict__ Wb,      // [F_OUT][K2]
    const float* __restrict__ bias,
    float* __restrict__ out) {          // [N][F_OUT]
  int tid = threadIdx.x;
  int wave = tid >> 6;
  int lane = tid & 63;
  int m0 = blockIdx.x * 16;             // 625 * 16 == 10000 exactly
  int r15 = lane & 15;
  int kq = lane >> 4;
  int node = m0 + r15;
  int col0 = wave * 64;

  const __bf16* arow_f = featb + (size_t)node * F;
  const __bf16* arow_a = aggb + (size_t)node * F;

  f32x4 acc[4];
#pragma unroll
  for (int c = 0; c < 4; ++c) acc[c] = (f32x4){0.f, 0.f, 0.f, 0.f};

#pragma unroll
  for (int t = 0; t < 16; ++t) {
    int kk = t * 32 + kq * 8;
    bf16x8 a;
    if (t < 8) a = *(const bf16x8*)(arow_f + kk);
    else       a = *(const bf16x8*)(arow_a + (kk - F));
#pragma unroll
    for (int c = 0; c < 4; ++c) {
      const __bf16* brow = Wb + (size_t)(col0 + c * 16 + r15) * K2 + kk;
      bf16x8 b = *(const bf16x8*)brow;
      acc[c] = __builtin_amdgcn_mfma_f32_16x16x32_bf16(a, b, acc[c], 0, 0, 0);
    }
  }

  // C/D layout: col = lane&15, row = (lane>>4)*4 + reg   [m89-verified]
  int rbase = kq * 4;
#pragma unroll
  for (int c = 0; c < 4; ++c) {
    int col = col0 + c * 16 + r15;
    float bv = bias[col];
#pragma unroll
    for (int r = 0; r < 4; ++r) {
      int orow = m0 + rbase + r;
      out[(size_t)orow * F + col] = fmaxf(acc[c][r] + bv, 0.0f);
    }
  }
}

extern "C" void kernel_launch(void* const* d_in, const int* in_sizes, int n_in,
                              void* d_out, int out_size, void* d_ws, size_t ws_size,
                              hipStream_t stream) {
  const float* feat = (const float*)d_in[0];
  const float* ew   = (const float*)d_in[1];
  const int*   src  = (const int*)d_in[2];
  const int*   dst  = (const int*)d_in[3];
  const float* Wm   = (const float*)d_in[4];
  const float* bias = (const float*)d_in[5];
  float* out = (float*)d_out;

  // workspace layout (8B-aligned first)
  u64*    epack = (u64*)d_ws;                                  // E
  __bf16* featb = (__bf16*)(epack + N_EDGES);                  // N*F
  __bf16* aggb  = featb + (size_t)N_NODES * F;                 // N*F
  __bf16* Wb    = aggb + (size_t)N_NODES * F;                  // F*K2
  int*    off   = (int*)(Wb + (size_t)F * K2);                 // N+1
  int*    cursor= off + N_NODES + 1;                           // N
  int*    deg   = cursor + N_NODES;                            // N

  prep_all_kernel<<<FEAT_BLOCKS + W_BLOCKS, 256, 0, stream>>>(feat, Wm, src, featb, Wb, deg);

  hist_kernel<<<(N_EDGES + 255) / 256, 256, 0, stream>>>(dst, deg);
  scan_kernel<<<1, SCAN_T, 0, stream>>>(deg, off, cursor);
  scatter_kernel<<<(N_EDGES + 255) / 256, 256, 0, stream>>>(src, dst, ew, cursor, epack);

  node_agg_kernel<<<(N_NODES * 64 + 255) / 256, 256, 0, stream>>>(featb, off, epack, aggb);

  mfma_gemm_kernel<<<N_NODES / 16, 256, 0, stream>>>(featb, aggb, Wb, bias, out);
}

// Round 5
// 102.193 us; speedup vs baseline: 11.5738x; 1.1509x over previous
//
#include <hip/hip_runtime.h>

#define N_NODES 10000
#define N_EDGES 320000
#define F 256          // F_IN == F_OUT
#define K2 512         // 2*F_IN
#define SCAN_T 1024
#define SCAN_CH 10     // 1024*10 = 10240 >= N_NODES

#define FEAT_BLOCKS (N_NODES * F / 4 / 256)   // 2500
#define W_BLOCKS (F * K2 / 4 / 256)           // 128

typedef __attribute__((ext_vector_type(8))) __bf16 bf16x8;
typedef __attribute__((ext_vector_type(4))) __bf16 bf16x4;
typedef __attribute__((ext_vector_type(4))) float f32x4;
typedef unsigned long long u64;
typedef unsigned int u32;
typedef unsigned short u16;

__device__ inline float bf2f(u16 u) { u32 x = ((u32)u) << 16; return __uint_as_float(x); }

// Tiled A layout: AT[tile][t][kq][n16][8e], tile=node/16, t=k/32 (k in [0,512)),
// kq=(k%32)/8, e=k%8. One (tile,t) block = 1KB contiguous = one wave's A-fragment.
// Tiled W layout: Wt[t][kq][col][8e].

// ---------- fused prep: featb plain + AT feat-half + Wt (h0 folded) + deg=0
__global__ __launch_bounds__(256) void prep_all_kernel(
    const float* __restrict__ feat,
    const float* __restrict__ Wm,
    const int* __restrict__ src,
    __bf16* __restrict__ featb,
    __bf16* __restrict__ AT,
    __bf16* __restrict__ Wt,
    int* __restrict__ deg) {
  int b = blockIdx.x;
  int tid = threadIdx.x;
  if (b < FEAT_BLOCKS) {
    int idx = b * 256 + tid;                         // float4 index over feat
    int node = idx >> 6;                             // 64 float4 per row
    int k = (idx & 63) * 4;
    float4 v = ((const float4*)feat)[idx];
    bf16x4 o;
    o[0] = (__bf16)v.x; o[1] = (__bf16)v.y; o[2] = (__bf16)v.z; o[3] = (__bf16)v.w;
    *(bf16x4*)(featb + (size_t)idx * 4) = o;         // plain row-major (for gather)
    int tile = node >> 4, n16 = node & 15;
    int t = k >> 5, kq = (k & 31) >> 3, e = k & 7;
    size_t off = ((((size_t)tile * 16 + t) * 4 + kq) * 16 + n16) * 8 + e;
    *(bf16x4*)(AT + off) = o;                        // fragment-tiled feat half
    if (idx < N_NODES) deg[idx] = 0;
  } else {
    int idx = (b - FEAT_BLOCKS) * 256 + tid;         // float4 index over W
    int o_ = idx >> 7;                               // 128 float4 per W row
    int k = (idx & 127) * 4;
    float4 w = ((const float4*)Wm)[idx];
    if (k >= F) {
      int s0 = src[0];
      float4 h = ((const float4*)(feat + (size_t)s0 * F))[(k - F) >> 2];
      w.x *= h.x; w.y *= h.y; w.z *= h.z; w.w *= h.w;
    }
    bf16x4 o;
    o[0] = (__bf16)w.x; o[1] = (__bf16)w.y; o[2] = (__bf16)w.z; o[3] = (__bf16)w.w;
    int t = k >> 5, kq = (k & 31) >> 3, e = k & 7;
    size_t off = (((size_t)t * 4 + kq) * 256 + o_) * 8 + e;
    *(bf16x4*)(Wt + off) = o;
  }
}

// ---------- CSR build step 1: histogram of dst (4 edges/thread)
__global__ __launch_bounds__(256) void hist_kernel(const int* __restrict__ dst,
                                                   int* __restrict__ deg) {
  int i = blockIdx.x * 256 + threadIdx.x;
  if (i >= N_EDGES / 4) return;
  int4 d = ((const int4*)dst)[i];
  atomicAdd(&deg[d.x], 1);
  atomicAdd(&deg[d.y], 1);
  atomicAdd(&deg[d.z], 1);
  atomicAdd(&deg[d.w], 1);
}

// ---------- CSR build step 2: exclusive scan (single block, 1024 thr)
__global__ __launch_bounds__(SCAN_T) void scan_kernel(const int* __restrict__ deg,
                                                      int* __restrict__ off,
                                                      int* __restrict__ cursor) {
  __shared__ int part[SCAN_T];
  int t = threadIdx.x;
  int base = t * SCAN_CH;
  int local[SCAN_CH];
  int s = 0;
  for (int j = 0; j < SCAN_CH; ++j) {
    int i = base + j;
    int d = (i < N_NODES) ? deg[i] : 0;
    local[j] = s;
    s += d;
  }
  part[t] = s;
  __syncthreads();
  for (int ofs = 1; ofs < SCAN_T; ofs <<= 1) {
    int v = (t >= ofs) ? part[t - ofs] : 0;
    __syncthreads();
    part[t] += v;
    __syncthreads();
  }
  int excl = part[t] - s;
  for (int j = 0; j < SCAN_CH; ++j) {
    int i = base + j;
    if (i < N_NODES) {
      int o = excl + local[j];
      off[i] = o;
      cursor[i] = o;
    }
  }
  if (t == SCAN_T - 1) off[N_NODES] = part[SCAN_T - 1];
}

// ---------- CSR build step 3: scatter packed (ew,src), 4 edges/thread
__global__ __launch_bounds__(256) void scatter_kernel(const int* __restrict__ src,
                                                      const int* __restrict__ dst,
                                                      const float* __restrict__ ew,
                                                      int* __restrict__ cursor,
                                                      u64* __restrict__ epack) {
  int i = blockIdx.x * 256 + threadIdx.x;
  if (i >= N_EDGES / 4) return;
  int4 s4 = ((const int4*)src)[i];
  int4 d4 = ((const int4*)dst)[i];
  float4 w4 = ((const float4*)ew)[i];
  int p;
  p = atomicAdd(&cursor[d4.x], 1);
  epack[p] = ((u64)__float_as_uint(w4.x) << 32) | (u32)s4.x;
  p = atomicAdd(&cursor[d4.y], 1);
  epack[p] = ((u64)__float_as_uint(w4.y) << 32) | (u32)s4.y;
  p = atomicAdd(&cursor[d4.z], 1);
  epack[p] = ((u64)__float_as_uint(w4.z) << 32) | (u32)s4.z;
  p = atomicAdd(&cursor[d4.w], 1);
  epack[p] = ((u64)__float_as_uint(w4.w) << 32) | (u32)s4.w;
}

// ---------- aggregation: one wave per node, 4-deep gather, writes AT agg-half
__global__ __launch_bounds__(256) void node_agg_kernel(
    const __bf16* __restrict__ featb,
    const int* __restrict__ off,
    const u64* __restrict__ epack,
    __bf16* __restrict__ AT) {
  int node = (blockIdx.x * 256 + threadIdx.x) >> 6;
  int lane = threadIdx.x & 63;
  if (node >= N_NODES) return;
  int beg = off[node], end = off[node + 1];
  float ax = 0.f, ay = 0.f, az = 0.f, aw = 0.f;
  const ushort4* f4 = (const ushort4*)featb;
  int i = beg;
  for (; i + 4 <= end; i += 4) {
    u64 p0 = epack[i], p1 = epack[i + 1], p2 = epack[i + 2], p3 = epack[i + 3];
    ushort4 v0 = f4[(size_t)(u32)p0 * 64 + lane];
    ushort4 v1 = f4[(size_t)(u32)p1 * 64 + lane];
    ushort4 v2 = f4[(size_t)(u32)p2 * 64 + lane];
    ushort4 v3 = f4[(size_t)(u32)p3 * 64 + lane];
    float w0 = __uint_as_float((u32)(p0 >> 32));
    float w1 = __uint_as_float((u32)(p1 >> 32));
    float w2 = __uint_as_float((u32)(p2 >> 32));
    float w3 = __uint_as_float((u32)(p3 >> 32));
    ax += bf2f(v0.x) * w0 + bf2f(v1.x) * w1 + bf2f(v2.x) * w2 + bf2f(v3.x) * w3;
    ay += bf2f(v0.y) * w0 + bf2f(v1.y) * w1 + bf2f(v2.y) * w2 + bf2f(v3.y) * w3;
    az += bf2f(v0.z) * w0 + bf2f(v1.z) * w1 + bf2f(v2.z) * w2 + bf2f(v3.z) * w3;
    aw += bf2f(v0.w) * w0 + bf2f(v1.w) * w1 + bf2f(v2.w) * w2 + bf2f(v3.w) * w3;
  }
  for (; i < end; ++i) {
    u64 p0 = epack[i];
    ushort4 v0 = f4[(size_t)(u32)p0 * 64 + lane];
    float w0 = __uint_as_float((u32)(p0 >> 32));
    ax += bf2f(v0.x) * w0; ay += bf2f(v0.y) * w0;
    az += bf2f(v0.z) * w0; aw += bf2f(v0.w) * w0;
  }
  float ic = 1.0f / (float)max(end - beg, 1);
  bf16x4 o;
  o[0] = (__bf16)(ax * ic); o[1] = (__bf16)(ay * ic);
  o[2] = (__bf16)(az * ic); o[3] = (__bf16)(aw * ic);
  // write into AT agg-half: lane covers k_agg = lane*4 .. +3
  int tile = node >> 4, n16 = node & 15;
  int t = 8 + (lane >> 3);
  int kq = (lane & 7) >> 1;
  int e = (lane & 1) * 4;
  size_t offT = ((((size_t)tile * 16 + t) * 4 + kq) * 16 + n16) * 8 + e;
  *(bf16x4*)(AT + offT) = o;
}

// ---------- MFMA GEMM on tiled operands: out = relu(AT @ Wt + b)
__global__ __launch_bounds__(256) void mfma_gemm_kernel(
    const __bf16* __restrict__ AT,      // [625][16][4][16][8]
    const __bf16* __restrict__ Wt,      // [16][4][256][8]
    const float* __restrict__ bias,
    float* __restrict__ out) {          // [N][F_OUT]
  int tid = threadIdx.x;
  int wave = tid >> 6;
  int lane = tid & 63;
  int r15 = lane & 15;
  int kq = lane >> 4;
  int tile = blockIdx.x;                // 625 tiles of 16 nodes
  int col0 = wave * 64;

  const __bf16* Ab = AT + (size_t)tile * 8192;   // 16 nodes x 512 k

  f32x4 acc[4];
#pragma unroll
  for (int c = 0; c < 4; ++c) acc[c] = (f32x4){0.f, 0.f, 0.f, 0.f};

#pragma unroll
  for (int t = 0; t < 16; ++t) {
    bf16x8 a = *(const bf16x8*)(Ab + (((size_t)t * 4 + kq) * 16 + r15) * 8);
#pragma unroll
    for (int c = 0; c < 4; ++c) {
      bf16x8 bb = *(const bf16x8*)(Wt + (((size_t)t * 4 + kq) * 256 + col0 + c * 16 + r15) * 8);
      acc[c] = __builtin_amdgcn_mfma_f32_16x16x32_bf16(a, bb, acc[c], 0, 0, 0);
    }
  }

  // C/D layout: col = lane&15, row = (lane>>4)*4 + reg   [m89-verified]
  int m0 = tile * 16;
  int rbase = kq * 4;
#pragma unroll
  for (int c = 0; c < 4; ++c) {
    int col = col0 + c * 16 + r15;
    float bv = bias[col];
#pragma unroll
    for (int r = 0; r < 4; ++r) {
      int orow = m0 + rbase + r;
      out[(size_t)orow * F + col] = fmaxf(acc[c][r] + bv, 0.0f);
    }
  }
}

extern "C" void kernel_launch(void* const* d_in, const int* in_sizes, int n_in,
                              void* d_out, int out_size, void* d_ws, size_t ws_size,
                              hipStream_t stream) {
  const float* feat = (const float*)d_in[0];
  const float* ew   = (const float*)d_in[1];
  const int*   src  = (const int*)d_in[2];
  const int*   dst  = (const int*)d_in[3];
  const float* Wm   = (const float*)d_in[4];
  const float* bias = (const float*)d_in[5];
  float* out = (float*)d_out;

  // workspace layout (8B-aligned first)
  u64*    epack = (u64*)d_ws;                                  // E
  __bf16* featb = (__bf16*)(epack + N_EDGES);                  // N*F plain
  __bf16* AT    = featb + (size_t)N_NODES * F;                 // N*K2 tiled
  __bf16* Wt    = AT + (size_t)N_NODES * K2;                   // F*K2 tiled
  int*    off   = (int*)(Wt + (size_t)F * K2);                 // N+1
  int*    cursor= off + N_NODES + 1;                           // N
  int*    deg   = cursor + N_NODES;                            // N

  prep_all_kernel<<<FEAT_BLOCKS + W_BLOCKS, 256, 0, stream>>>(feat, Wm, src, featb, AT, Wt, deg);

  hist_kernel<<<(N_EDGES / 4 + 255) / 256, 256, 0, stream>>>(dst, deg);
  scan_kernel<<<1, SCAN_T, 0, stream>>>(deg, off, cursor);
  scatter_kernel<<<(N_EDGES / 4 + 255) / 256, 256, 0, stream>>>(src, dst, ew, cursor, epack);

  node_agg_kernel<<<(N_NODES * 64 + 255) / 256, 256, 0, stream>>>(featb, off, epack, AT);

  mfma_gemm_kernel<<<N_NODES / 16, 256, 0, stream>>>(AT, Wt, bias, out);
}